// Round 1
// baseline (288.662 us; speedup 1.0000x reference)
//
#include <hip/hip_runtime.h>
#include <math.h>

typedef __attribute__((ext_vector_type(8))) short short8;
typedef __attribute__((ext_vector_type(4))) float f32x4;

#define NJ 24

// ---- ws image layout (units: shorts/bf16) ----
#define W1T_JSTR   (80*104)                 // 8320 shorts per joint: [n=80][k'=104]
#define W2T_OFFS   (NJ*W1T_JSTR)            // 199680
#define W2T_JSTR   (64*104)                 // 6656: [n=64][k=104]
#define WPT_OFFS   (W2T_OFFS + NJ*W2T_JSTR) // 359424
#define WPT_CSTR   (64*104)                 // 6656 per 64-wide K chunk of Wp^T
#define IMG_SHORTS (WPT_OFFS + 5*WPT_CSTR)  // 392704 shorts = 785408 bytes in d_ws

__device__ __forceinline__ short f2bf(float f) {
  union { float f; unsigned u; } v; v.f = f;
  unsigned r = v.u + 0x7FFFu + ((v.u >> 16) & 1u);   // RNE
  return (short)(r >> 16);
}

// Pad + transpose + bf16-cast all weights once into d_ws (MFMA B-operand layout).
__global__ __launch_bounds__(256) void prep_kernel(
    const float* __restrict__ W1, const float* __restrict__ W2,
    const float* __restrict__ Wp, short* __restrict__ img) {
  int t = blockIdx.x * 256 + threadIdx.x;
  if (t >= IMG_SHORTS) return;
  float v = 0.f;
  if (t < W2T_OFFS) {                       // W1^T, with k-remap: k<13 -> k ; k>=13 -> k+3
    int j = t / W1T_JSTR, r = t % W1T_JSTR;
    int n = r / 104, kp = r % 104;
    if (n < 77) {
      if (kp < 13)                  v = W1[j*5929 + kp*77 + n];
      else if (kp >= 16 && kp < 80) v = W1[j*5929 + (kp-3)*77 + n];
    }
  } else if (t < WPT_OFFS) {                // W2^T, no remap (h is contiguous 0..76)
    int u = t - W2T_OFFS;
    int j = u / W2T_JSTR, r = u % W2T_JSTR;
    int n = r / 104, kp = r % 104;
    if (kp < 77) v = W2[j*4928 + kp*64 + n];
  } else {                                  // Wp^T in 5 chunks of 64 K-columns
    int u = t - WPT_OFFS;
    int c = u / WPT_CSTR, r = u % WPT_CSTR;
    int n = r / 104, kk = r % 104;
    int gk = c*64 + kk;
    if (kk < 64 && gk < 288) v = Wp[gk*64 + n];
  }
  img[t] = f2bf(v);
}

// Main kernel: 64 batch rows / WG, 8 waves = 4 m-tiles x 2 n-halves.
// x layout (K'=96): [0..12]=bone_transform, [13..15]=0, [16..79]=parent feat, [80..95]=0
__global__ __launch_bounds__(512, 4) void enc_kernel(
    const float* __restrict__ pose, const float* __restrict__ rel,
    const float* __restrict__ bp,  const float* __restrict__ b1,
    const float* __restrict__ b2,  const short* __restrict__ img,
    float* __restrict__ out) {
  __shared__ __align__(16) short featL[4*64*72];  // 4 feat slots, stride 72 (conflict-free)
  __shared__ __align__(16) short btL[64*24];      // bone transforms, cols 13..23 stay 0
  __shared__ __align__(16) short hL[64*88];       // h tile, cols 80..87 stay 0
  __shared__ __align__(16) short w1L[80*104];     // W1^T image
  __shared__ __align__(16) short w2L[64*104];     // W2^T image
  // total 81,152 B -> 2 WG/CU

  const int tid  = threadIdx.x;
  const int lane = tid & 63;
  const int wid  = tid >> 6;
  const int mt   = wid & 3;        // m-tile (16 rows)
  const int nh   = wid >> 2;       // n-half
  const int rm   = lane & 15;
  const int g    = lane >> 4;      // k-octet group / D-row group
  const int rb   = blockIdx.x * 64;
  const int row  = mt*16 + rm;     // A-fragment row within WG tile

  // one-time zero pads
  for (int t = tid; t < 64*11; t += 512) { int r = t/11, c = 13 + (t%11); btL[r*24 + c] = 0; }
  for (int t = tid; t < 64*8;  t += 512) { int r = t>>3,  c = 80 + (t&7); hL[r*88 + c]  = 0; }

  // ======== root prior: bonefeat(64x288) @ Wp(288x64) + bp -> feat slot 3 (no relu) ====
  f32x4 racc0 = {0.f,0.f,0.f,0.f}, racc1 = {0.f,0.f,0.f,0.f};
#pragma unroll 1
  for (int c = 0; c < 5; ++c) {
    const int kw = (c < 4) ? 64 : 32;
    const int sh = (c < 4) ? 6 : 5;
    __syncthreads();
    { // stage Wp^T chunk -> w1L (flat copy, identical [n][104] layout)
      const short8* src = (const short8*)(img + WPT_OFFS + c*WPT_CSTR);
      short8* dst = (short8*)w1L;
      for (int t = tid; t < 832; t += 512) dst[t] = src[t];
    }
    // stage bone-feature chunk -> hL rows (cols 0..kw-1)
    for (int t = tid; t < (64 << sh); t += 512) {
      int r = t >> sh, cc = t & (kw - 1);
      int kglob = c*64 + cc;
      int j = kglob / 12, w = kglob % 12;
      float v = (w < 9) ? pose[(size_t)(rb + r)*216 + (size_t)(j*9 + w)]
                        : rel [(size_t)(rb + r)*72  + (size_t)(j*3 + (w - 9))];
      hL[r*88 + cc] = f2bf(v);
    }
    __syncthreads();
    const int ks = kw >> 5;
#pragma unroll 1
    for (int s = 0; s < ks; ++s) {
      short8 a  = *(const short8*)(hL + row*88 + s*32 + g*8);
      short8 bA = *(const short8*)(w1L + ((nh*32 +  0) + rm)*104 + s*32 + g*8);
      short8 bB = *(const short8*)(w1L + ((nh*32 + 16) + rm)*104 + s*32 + g*8);
      racc0 = __builtin_amdgcn_mfma_f32_16x16x32_bf16(a, bA, racc0, 0, 0, 0);
      racc1 = __builtin_amdgcn_mfma_f32_16x16x32_bf16(a, bB, racc1, 0, 0, 0);
    }
  }
  {
    int n0 = nh*32 + rm, n1 = nh*32 + 16 + rm;
    float p0 = bp[n0], p1 = bp[n1];
#pragma unroll
    for (int r4 = 0; r4 < 4; ++r4) {
      int rr = mt*16 + g*4 + r4;
      featL[3*4608 + rr*72 + n0] = f2bf(racc0[r4] + p0);
      featL[3*4608 + rr*72 + n1] = f2bf(racc1[r4] + p1);
    }
  }

  // slot schedule (verified liveness over PARENTS): 2-bit packed
  const unsigned long long PS_PACK = 0x4E4E15393903ULL; // parent slot per joint
  const unsigned long long SS_PACK = 0x04E43804E4E4ULL; // store  slot per joint
  const unsigned LEAF = 0x00C08C00u;                    // joints 10,11,15,22,23

#pragma unroll 1
  for (int i = 0; i < NJ; ++i) {
    __syncthreads();
    { // stage W1^T (1040 x 16B) and W2^T (832 x 16B) from L2-resident images
      const short8* s1 = (const short8*)(img + i*W1T_JSTR);
      short8* d1 = (short8*)w1L;
      for (int t = tid; t < 1040; t += 512) d1[t] = s1[t];
      const short8* s2 = (const short8*)(img + W2T_OFFS + i*W2T_JSTR);
      short8* d2 = (short8*)w2L;
      for (int t = tid; t < 832; t += 512) d2[t] = s2[t];
    }
    // stage bone transforms: cols 0..8 pose, 9..11 rel, 12 = |rel|
    for (int t = tid; t < 1024; t += 512) {
      int r = t >> 4, cc = t & 15;
      size_t pb = (size_t)(rb + r)*216 + (size_t)i*9;
      size_t rl = (size_t)(rb + r)*72  + (size_t)i*3;
      if (cc < 9)       btL[r*24 + cc] = f2bf(pose[pb + cc]);
      else if (cc < 12) btL[r*24 + cc] = f2bf(rel[rl + (cc-9)]);
      else if (cc == 12) {
        float x0 = rel[rl], x1 = rel[rl+1], x2 = rel[rl+2];
        btL[r*24 + 12] = f2bf(sqrtf(x0*x0 + x1*x1 + x2*x2));
      }
    }
    __syncthreads();

    // ---- GEMM1: h = relu(x @ W1 + b1), K'=96 ----
    const int ps = (int)((PS_PACK >> (2*i)) & 3ull);
    const short* fb = featL + ps*4608 + row*72;
    short8 a0 = (g < 2) ? *(const short8*)(btL + row*24 + g*8)     // k' 0..15
                        : *(const short8*)(fb + (g-2)*8);          // k' 16..31 = feat 0..15
    short8 a1 = *(const short8*)(fb + 16 + g*8);                   // k' 32..63 = feat 16..47
    short8 a2 = (g < 2) ? *(const short8*)(fb + 48 + g*8)          // k' 64..79 = feat 48..63
                        : *(const short8*)(btL + row*24 + 16);     // k' 80..95 = zeros
    const int nt0 = nh ? 3 : 0;
    const int ntc = nh ? 2 : 3;
#pragma unroll 1
    for (int q = 0; q < ntc; ++q) {
      int nt = nt0 + q;
      const short* wb = w1L + (nt*16 + rm)*104 + g*8;
      f32x4 acc = {0.f,0.f,0.f,0.f};
      acc = __builtin_amdgcn_mfma_f32_16x16x32_bf16(a0, *(const short8*)(wb),      acc, 0,0,0);
      acc = __builtin_amdgcn_mfma_f32_16x16x32_bf16(a1, *(const short8*)(wb + 32), acc, 0,0,0);
      acc = __builtin_amdgcn_mfma_f32_16x16x32_bf16(a2, *(const short8*)(wb + 64), acc, 0,0,0);
      int n = nt*16 + rm;
      float bias = (n < 77) ? b1[i*77 + n] : 0.f;
#pragma unroll
      for (int r4 = 0; r4 < 4; ++r4) {
        float v = fmaxf(acc[r4] + bias, 0.f);
        hL[(mt*16 + g*4 + r4)*88 + n] = f2bf(v);
      }
    }
    __syncthreads();

    // ---- GEMM2: f = relu(h @ W2 + b2), K=96 (cols 80..95 zero) ----
    short8 h0 = *(const short8*)(hL + row*88 + g*8);
    short8 h1 = *(const short8*)(hL + row*88 + 32 + g*8);
    int c2 = 64 + g*8; if (c2 > 80) c2 = 80;                       // g=3 -> zero region
    short8 h2 = *(const short8*)(hL + row*88 + c2);
    int ss = ((LEAF >> i) & 1u) ? -1 : (int)((SS_PACK >> (2*i)) & 3ull);
#pragma unroll 1
    for (int q = 0; q < 2; ++q) {
      int nt = nh*2 + q;
      const short* wb = w2L + (nt*16 + rm)*104 + g*8;
      f32x4 acc = {0.f,0.f,0.f,0.f};
      acc = __builtin_amdgcn_mfma_f32_16x16x32_bf16(h0, *(const short8*)(wb),      acc, 0,0,0);
      acc = __builtin_amdgcn_mfma_f32_16x16x32_bf16(h1, *(const short8*)(wb + 32), acc, 0,0,0);
      acc = __builtin_amdgcn_mfma_f32_16x16x32_bf16(h2, *(const short8*)(wb + 64), acc, 0,0,0);
      int n = nt*16 + rm;
      float bias = b2[i*64 + n];
#pragma unroll
      for (int r4 = 0; r4 < 4; ++r4) {
        float v = fmaxf(acc[r4] + bias, 0.f);
        int rr = mt*16 + g*4 + r4;
        out[(size_t)(rb + rr)*1536 + (size_t)(i*64 + n)] = v;   // f32 output (pre-bf16)
        if (ss >= 0) featL[ss*4608 + rr*72 + n] = f2bf(v);      // bf16 feat for children
      }
    }
  }
}

extern "C" void kernel_launch(void* const* d_in, const int* in_sizes, int n_in,
                              void* d_out, int out_size, void* d_ws, size_t ws_size,
                              hipStream_t stream) {
  const float* pose = (const float*)d_in[0];
  const float* rel  = (const float*)d_in[1];
  const float* Wp   = (const float*)d_in[2];
  const float* bp   = (const float*)d_in[3];
  const float* W1   = (const float*)d_in[4];
  const float* b1   = (const float*)d_in[5];
  const float* W2   = (const float*)d_in[6];
  const float* b2   = (const float*)d_in[7];
  float* outp = (float*)d_out;
  short* img  = (short*)d_ws;            // 785,408 bytes of scratch
  const int Bn = in_sizes[0] / 216;      // pose is B*24*9
  prep_kernel<<<(IMG_SHORTS + 255)/256, 256, 0, stream>>>(W1, W2, Wp, img);
  enc_kernel<<<Bn/64, 512, 0, stream>>>(pose, rel, bp, b1, b2, img, outp);
}

// Round 2
// 267.667 us; speedup vs baseline: 1.0784x; 1.0784x over previous
//
#include <hip/hip_runtime.h>
#include <hip/hip_bf16.h>
#include <math.h>

typedef __attribute__((ext_vector_type(8))) short short8;
typedef __attribute__((ext_vector_type(4))) float f32x4;

#define NJ 24

// ---- ws image layout (units: shorts/bf16) ----
#define W1T_JSTR   (80*104)                 // 8320 shorts per joint: [n=80][k'=104]
#define W2T_OFFS   (NJ*W1T_JSTR)            // 199680
#define W2T_JSTR   (64*104)                 // 6656: [n=64][k=104]
#define WPT_OFFS   (W2T_OFFS + NJ*W2T_JSTR) // 359424
#define WPT_CSTR   (64*104)                 // 6656 per 64-wide K chunk of Wp^T
#define IMG_SHORTS (WPT_OFFS + 5*WPT_CSTR)  // 392704 shorts = 785408 bytes in d_ws

__device__ __forceinline__ short f2bf(float f) {      // cold path (prep only)
  union { float f; unsigned u; } v; v.f = f;
  unsigned r = v.u + 0x7FFFu + ((v.u >> 16) & 1u);    // RNE
  return (short)(r >> 16);
}

__device__ __forceinline__ short sbf(float f) {       // hot path: 1-2 inst cvt
  __hip_bfloat16 h = __float2bfloat16(f);
  return *reinterpret_cast<short*>(&h);
}

// async global->LDS, 16B per lane; lds dest = wave-uniform base + lane*16
__device__ __forceinline__ void load_lds16(const void* g, void* l) {
  __builtin_amdgcn_global_load_lds(
      (const __attribute__((address_space(1))) void*)g,
      (__attribute__((address_space(3))) void*)l, 16, 0, 0);
}

// flat copy of n16 16-byte chunks, 512 threads; exec-masked partial tail ok
__device__ __forceinline__ void stage_flat(const short* __restrict__ src,
                                           short* dst, int n16, int tid, int lane) {
#pragma unroll 1
  for (int t = tid; t < n16; t += 512)
    load_lds16(src + (size_t)t * 8, dst + (t - lane) * 8);
}

// Pad + transpose + bf16-cast all weights once into d_ws (MFMA B-operand layout).
__global__ __launch_bounds__(256) void prep_kernel(
    const float* __restrict__ W1, const float* __restrict__ W2,
    const float* __restrict__ Wp, short* __restrict__ img) {
  int t = blockIdx.x * 256 + threadIdx.x;
  if (t >= IMG_SHORTS) return;
  float v = 0.f;
  if (t < W2T_OFFS) {                       // W1^T, k-remap: k<13 -> k ; k>=13 -> k+3
    int j = t / W1T_JSTR, r = t % W1T_JSTR;
    int n = r / 104, kp = r % 104;
    if (n < 77) {
      if (kp < 13)                  v = W1[j*5929 + kp*77 + n];
      else if (kp >= 16 && kp < 80) v = W1[j*5929 + (kp-3)*77 + n];
    }
  } else if (t < WPT_OFFS) {                // W2^T (h is contiguous 0..76)
    int u = t - W2T_OFFS;
    int j = u / W2T_JSTR, r = u % W2T_JSTR;
    int n = r / 104, kp = r % 104;
    if (kp < 77) v = W2[j*4928 + kp*64 + n];
  } else {                                  // Wp^T in 5 chunks of 64 K-columns
    int u = t - WPT_OFFS;
    int c = u / WPT_CSTR, r = u % WPT_CSTR;
    int n = r / 104, kk = r % 104;
    int gk = c*64 + kk;
    if (kk < 64 && gk < 288) v = Wp[gk*64 + n];
  }
  img[t] = f2bf(v);
}

// stage bone transforms for joint jj: cols 0..8 pose, 9..11 rel, 12 = |rel|
__device__ __forceinline__ void stage_bt(short* btL, const float* __restrict__ pose,
                                         const float* __restrict__ rel,
                                         int rb, int jj, int tid) {
#pragma unroll 1
  for (int t = tid; t < 1024; t += 512) {
    int r = t >> 4, cc = t & 15;
    size_t pb = (size_t)(rb + r)*216 + (size_t)jj*9;
    size_t rl = (size_t)(rb + r)*72  + (size_t)jj*3;
    if (cc < 9)       btL[r*24 + cc] = sbf(pose[pb + cc]);
    else if (cc < 12) btL[r*24 + cc] = sbf(rel[rl + (cc-9)]);
    else if (cc == 12) {
      float x0 = rel[rl], x1 = rel[rl+1], x2 = rel[rl+2];
      btL[r*24 + 12] = sbf(sqrtf(x0*x0 + x1*x1 + x2*x2));
    }
  }
}

// Main kernel: 64 batch rows / WG, 8 waves = 4 m-tiles x 2 n-halves.
// x layout (K'=96): [0..12]=bone_transform, [13..15]=0, [16..79]=parent feat, [80..95]=0
// Staging is software-staggered: every global->LDS load is issued one barrier
// ahead of its first use, so the barrier's vmcnt(0) drain hides all latency.
__global__ __launch_bounds__(512, 4) void enc_kernel(
    const float* __restrict__ pose, const float* __restrict__ rel,
    const float* __restrict__ bp,  const float* __restrict__ b1,
    const float* __restrict__ b2,  const short* __restrict__ img,
    float* __restrict__ out) {
  __shared__ __align__(16) short featL[4*64*72];  // 4 feat slots, stride 72
  __shared__ __align__(16) short btL[64*24];      // bone transforms (cols 13..23 = 0)
  __shared__ __align__(16) short hL[64*88];       // h tile (cols 80..87 = 0)
  __shared__ __align__(16) short w1L[80*104];     // W1^T image
  __shared__ __align__(16) short w2L[64*104];     // W2^T image
  // total 81,152 B -> 2 WG/CU

  const int tid  = threadIdx.x;
  const int lane = tid & 63;
  const int wid  = tid >> 6;
  const int mt   = wid & 3;        // m-tile (16 rows)
  const int nh   = wid >> 2;       // n-half
  const int rm   = lane & 15;
  const int g    = lane >> 4;      // k-octet group / D-row group
  const int rb   = blockIdx.x * 64;
  const int row  = mt*16 + rm;     // A-fragment row within WG tile
  const int wcol = rm*104 + g*8;   // B-frag lane offset within a 16-col tile

  // ---------------- prologue: issue W1[0], Wp chunk0; pads; bf chunk0; bt[0] ----
  stage_flat(img, w1L, 1040, tid, lane);             // W1[0]  (free all root phase)
  stage_flat(img + WPT_OFFS, w2L, 832, tid, lane);   // Wp chunk 0

  for (int t = tid; t < 64*11; t += 512) { int r = t/11, c = 13 + (t%11); btL[r*24 + c] = 0; }
  for (int t = tid; t < 64*8;  t += 512) { int r = t>>3,  c = 80 + (t&7); hL[r*88 + c]  = 0; }

#pragma unroll 1
  for (int t = tid; t < 4096; t += 512) {            // bone-feature chunk 0 -> hL
    int r = t >> 6, cc = t & 63;
    int j = cc / 12, w = cc % 12;
    float v = (w < 9) ? pose[(size_t)(rb + r)*216 + (size_t)(j*9 + w)]
                      : rel [(size_t)(rb + r)*72  + (size_t)(j*3 + (w - 9))];
    hL[r*88 + cc] = sbf(v);
  }
  stage_bt(btL, pose, rel, rb, 0, tid);
  __syncthreads();

  // ---------------- root prior: bonefeat(64x288) @ Wp + bp -> feat slot 3 -------
  // Wp chunks double-buffered: even -> w2L, odd -> featL[slots 0,1]
  // bone-feature chunks:       even -> hL (stride 88), odd -> featL slot 2 (stride 72)
  f32x4 racc0 = {0.f,0.f,0.f,0.f}, racc1 = {0.f,0.f,0.f,0.f};
#pragma unroll 1
  for (int c = 0; c < 5; ++c) {
    if (c < 4)
      stage_flat(img + WPT_OFFS + (size_t)(c+1)*WPT_CSTR,
                 ((c+1)&1) ? featL : w2L, 832, tid, lane);
    const short* wp = (c&1) ? featL : w2L;
    const short* bf = (c&1) ? (featL + 2*4608) : hL;
    const int    sA = (c&1) ? 72 : 88;
    const int    ks = (c < 4) ? 2 : 1;
    const short* wbA = wp + (nh*32)*104 + wcol;
    const short* wbB = wp + (nh*32 + 16)*104 + wcol;
#pragma unroll
    for (int s = 0; s < 2; ++s) {
      if (s < ks) {
        short8 a = *(const short8*)(bf + row*sA + s*32 + g*8);
        racc0 = __builtin_amdgcn_mfma_f32_16x16x32_bf16(a, *(const short8*)(wbA + s*32), racc0, 0,0,0);
        racc1 = __builtin_amdgcn_mfma_f32_16x16x32_bf16(a, *(const short8*)(wbB + s*32), racc1, 0,0,0);
      }
    }
    if (c < 4) {  // stage bone-feature chunk c+1 into the other bf buffer
      short*    dbf = ((c+1)&1) ? (featL + 2*4608) : hL;
      const int dst = ((c+1)&1) ? 72 : 88;
      const int kw  = (c+1 < 4) ? 64 : 32;
#pragma unroll 1
      for (int t = tid; t < 64*kw; t += 512) {
        int r = (kw == 64) ? (t >> 6) : (t >> 5);
        int cc = t & (kw - 1);
        int kglob = (c+1)*64 + cc;
        int j = kglob / 12, w = kglob % 12;
        float v = (w < 9) ? pose[(size_t)(rb + r)*216 + (size_t)(j*9 + w)]
                          : rel [(size_t)(rb + r)*72  + (size_t)(j*3 + (w - 9))];
        dbf[r*dst + cc] = sbf(v);
      }
      __syncthreads();
    }
  }
  { // root epilogue (no relu) -> feat slot 3; only touches slot 3, safe pre-barrier
    int n0 = nh*32 + rm, n1 = n0 + 16;
    float p0 = bp[n0], p1 = bp[n1];
#pragma unroll
    for (int r4 = 0; r4 < 4; ++r4) {
      int rr = mt*16 + g*4 + r4;
      featL[3*4608 + rr*72 + n0] = sbf(racc0[r4] + p0);
      featL[3*4608 + rr*72 + n1] = sbf(racc1[r4] + p1);
    }
  }
  __syncthreads();

  // slot schedule (verified liveness over PARENTS): 2-bit packed
  const unsigned long long PS_PACK = 0x4E4E15393903ULL; // parent slot per joint
  const unsigned long long SS_PACK = 0x04E43804E4E4ULL; // store  slot per joint
  const unsigned LEAF = 0x00C08C00u;                    // joints 10,11,15,22,23

  float* outr = out + (size_t)(rb + mt*16 + g*4)*1536;

#pragma unroll 1
  for (int i = 0; i < NJ; ++i) {
    // entry: w1L=W1[i], btL=bt[i], parent feats ready; w2L free
    stage_flat(img + W2T_OFFS + (size_t)i*W2T_JSTR, w2L, 832, tid, lane);  // W2[i] async

    // ---- GEMM1: h = relu(x @ W1 + b1), K'=96 ----
    const int ps = (int)((PS_PACK >> (2*i)) & 3ull);
    const short* fb = featL + ps*4608 + row*72;
    short8 a0 = (g < 2) ? *(const short8*)(btL + row*24 + g*8)     // k' 0..15
                        : *(const short8*)(fb + (g-2)*8);          // k' 16..31
    short8 a1 = *(const short8*)(fb + 16 + g*8);                   // k' 32..63
    short8 a2 = (g < 2) ? *(const short8*)(fb + 48 + g*8)          // k' 64..79
                        : *(const short8*)(btL + row*24 + 16);     // k' 80..95 = 0
    const short* w1b = w1L + wcol;
    const float* b1i = b1 + i*77;
    const int hrow = (mt*16 + g*4)*88;
#define G1_TILE(NT) { \
      const short* wb = w1b + (NT)*1664; \
      f32x4 acc = {0.f,0.f,0.f,0.f}; \
      acc = __builtin_amdgcn_mfma_f32_16x16x32_bf16(a0, *(const short8*)(wb),      acc, 0,0,0); \
      acc = __builtin_amdgcn_mfma_f32_16x16x32_bf16(a1, *(const short8*)(wb + 32), acc, 0,0,0); \
      acc = __builtin_amdgcn_mfma_f32_16x16x32_bf16(a2, *(const short8*)(wb + 64), acc, 0,0,0); \
      const int n = (NT)*16 + rm; \
      const float bias = (n < 77) ? b1i[n] : 0.f; \
      _Pragma("unroll") \
      for (int r4 = 0; r4 < 4; ++r4) \
        hL[hrow + r4*88 + n] = sbf(fmaxf(acc[r4] + bias, 0.f)); \
    }
    if (nh == 0) { G1_TILE(0); G1_TILE(1); G1_TILE(2); }
    else         { G1_TILE(3); G1_TILE(4); }
#undef G1_TILE
    __syncthreads();   // B1: drains hL writes + W2[i] prefetch

    if (i < NJ-1)
      stage_flat(img + (size_t)(i+1)*W1T_JSTR, w1L, 1040, tid, lane);      // W1[i+1] async

    // ---- GEMM2: f = relu(h @ W2 + b2), K=96 (cols 80..95 zero) ----
    short8 h0 = *(const short8*)(hL + row*88 + g*8);
    short8 h1 = *(const short8*)(hL + row*88 + 32 + g*8);
    int c2 = 64 + g*8; if (c2 > 80) c2 = 80;
    short8 h2 = *(const short8*)(hL + row*88 + c2);
    const int ss = ((LEAF >> i) & 1u) ? -1 : (int)((SS_PACK >> (2*i)) & 3ull);
    const short* w2b = w2L + wcol;
    const float* b2i = b2 + i*64;
#define G2_TILE(Q) { \
      const int nt = nh*2 + (Q); \
      const short* wb = w2b + nt*1664; \
      f32x4 acc = {0.f,0.f,0.f,0.f}; \
      acc = __builtin_amdgcn_mfma_f32_16x16x32_bf16(h0, *(const short8*)(wb),      acc, 0,0,0); \
      acc = __builtin_amdgcn_mfma_f32_16x16x32_bf16(h1, *(const short8*)(wb + 32), acc, 0,0,0); \
      acc = __builtin_amdgcn_mfma_f32_16x16x32_bf16(h2, *(const short8*)(wb + 64), acc, 0,0,0); \
      const int n = nt*16 + rm; \
      const float bias = b2i[n]; \
      _Pragma("unroll") \
      for (int r4 = 0; r4 < 4; ++r4) { \
        float v = fmaxf(acc[r4] + bias, 0.f); \
        outr[(size_t)r4*1536 + i*64 + n] = v; \
        if (ss >= 0) featL[ss*4608 + (mt*16 + g*4 + r4)*72 + n] = sbf(v); \
      } \
    }
    G2_TILE(0); G2_TILE(1);
#undef G2_TILE

    if (i < NJ-1) stage_bt(btL, pose, rel, rb, i+1, tid);  // bt[i+1], overlaps GEMM2
    __syncthreads();   // BE: drains featL/btL writes + W1[i+1] prefetch
  }
}

extern "C" void kernel_launch(void* const* d_in, const int* in_sizes, int n_in,
                              void* d_out, int out_size, void* d_ws, size_t ws_size,
                              hipStream_t stream) {
  const float* pose = (const float*)d_in[0];
  const float* rel  = (const float*)d_in[1];
  const float* Wp   = (const float*)d_in[2];
  const float* bp   = (const float*)d_in[3];
  const float* W1   = (const float*)d_in[4];
  const float* b1   = (const float*)d_in[5];
  const float* W2   = (const float*)d_in[6];
  const float* b2   = (const float*)d_in[7];
  float* outp = (float*)d_out;
  short* img  = (short*)d_ws;            // 785,408 bytes of scratch
  const int Bn = in_sizes[0] / 216;      // pose is B*24*9
  prep_kernel<<<(IMG_SHORTS + 255)/256, 256, 0, stream>>>(W1, W2, Wp, img);
  enc_kernel<<<Bn/64, 512, 0, stream>>>(pose, rel, bp, b1, b2, img, outp);
}